// Round 9
// baseline (180.430 us; speedup 1.0000x reference)
//
#include <hip/hip_runtime.h>
#include <hip/hip_fp16.h>

#define HID 512
#define GC  640
#define CC  320
#define GG  2
#define DHALF 128
#define MARGIN 0.004f
#define FB 4
#define REPLD 324   // padded row stride (dwords) for the repack buffer

typedef __attribute__((ext_vector_type(8))) _Float16 half8;
typedef __attribute__((ext_vector_type(4))) float float4v;

__device__ __forceinline__ void gload16(const void* g, void* l) {
    __builtin_amdgcn_global_load_lds(
        (const __attribute__((address_space(1))) void*)(unsigned long long)g,
        (__attribute__((address_space(3))) void*)(unsigned)(unsigned long long)l,
        16, 0, 0);
}

__global__ __launch_bounds__(256) void zero_misc(float* meanAcc, int* cnt) {
    for (int i = threadIdx.x; i < GC; i += 256) meanAcc[i] = 0.f;
    if (threadIdx.x < 2) cnt[threadIdx.x] = 0;
}

__global__ __launch_bounds__(256) void convert_f16(
    const float* __restrict__ in, unsigned short* __restrict__ out, int n8)
{
    int i = blockIdx.x * 256 + threadIdx.x;
    if (i >= n8) return;
    const float4* p = (const float4*)in + (size_t)i * 2;
    float4 v0 = p[0], v1 = p[1];
    float f[8] = {v0.x, v0.y, v0.z, v0.w, v1.x, v1.y, v1.z, v1.w};
    unsigned r[4];
#pragma unroll
    for (int j = 0; j < 4; ++j) {
        __half2 hh = __float22half2_rn(make_float2(f[2*j], f[2*j+1]));
        r[j] = __builtin_bit_cast(unsigned, hh);
    }
    uint4 o = {r[0], r[1], r[2], r[3]};
    *(uint4*)(out + (size_t)i * 8) = o;
}

// Fused GEMM + LDS-repack epilogue (softmax-mean + argmax + gather).
// Block: 128 tokens x 320 codes (one group). 8 waves; each owns 16 rows x 320 cols.
// K-loop identical to round 8 (XOR-swizzled staging, 1 barrier/step, 0 conflicts).
// Epilogue: scores -> LDS (reusing As/Bs), 16-lane groups own whole tokens with
// 20 CONTIGUOUS codes/lane -> coalesced gum reads (round-5-proven pattern).
__global__ __launch_bounds__(512, 4) void fused(
    const float* __restrict__ X, const unsigned short* __restrict__ Wh,
    const float* __restrict__ bq, const float* __restrict__ gum,
    const float* __restrict__ cv, float* __restrict__ out,
    float* __restrict__ meanAcc, int* __restrict__ cnt,
    int* __restrict__ flags0, int* __restrict__ flags1)
{
    __shared__ __align__(16) char lds[57344];               // 56 KB: As(16K)+Bs(40K)
    unsigned short* As0 = (unsigned short*)lds;             // [2][4096]
    unsigned short* Bs0 = (unsigned short*)(lds + 16384);   // [2][10240]
    float* rep = (float*)lds;                               // epilogue: [32][REPLD]
    __shared__ float bqs[CC];
    __shared__ float smean[CC];

    const int tid  = threadIdx.x;
    const int lane = tid & 63;
    const int wid  = tid >> 6;          // 0..7
    const int lq   = lane & 15;
    const int q    = lane >> 4;

    int bid = blockIdx.x;
    int nwg = gridDim.x;
    int swz = ((nwg & 7) == 0) ? (bid & 7) * (nwg >> 3) + (bid >> 3) : bid;
    const int g    = swz & 1;
    const int tok0 = (swz >> 1) * 128;
    int* flagsg = g ? flags1 : flags0;

    for (int i = tid; i < CC; i += 512) { bqs[i] = bq[g * CC + i]; smean[i] = 0.f; }

    // ---- B staging (as round 8): XOR involution on SOURCE chunk, linear dest
    const int iss0 = wid, iss1 = wid + 8, iss2 = wid + 16;  // iss2 only wid<4
    const int c0i = (iss0 * 64 + lane) ^ (((iss0 * 64 + lane) >> 3) & 7);
    const int c1i = (iss1 * 64 + lane) ^ (((iss1 * 64 + lane) >> 3) & 7);
    const int c2i = (iss2 * 64 + lane) ^ (((iss2 * 64 + lane) >> 3) & 7);
    const unsigned short* srcB0 = Wh + ((size_t)(g * CC + (c0i >> 2))) * HID + (c0i & 3) * 8;
    const unsigned short* srcB1 = Wh + ((size_t)(g * CC + (c1i >> 2))) * HID + (c1i & 3) * 8;
    const unsigned short* srcB2 = Wh + ((size_t)(g * CC + (c2i >> 2))) * HID + (c2i & 3) * 8;

    // ---- A staging: linear dest chunk tid, swizzled source chunk
    const int ca = tid ^ ((tid >> 3) & 7);
    const float* xsrc = X + (size_t)(tok0 + (ca >> 2)) * HID + (ca & 3) * 8;

    // ---- swizzled read offsets (bytes)
    int aoff = ((wid * 16 + lq) << 6) + (q << 4);
    aoff ^= ((aoff >> 7) & 7) << 4;
    int boff = (lq << 6) + (q << 4);
    boff ^= (((lq >> 1) & 7) << 4);

    float4v acc[20];
#pragma unroll
    for (int j = 0; j < 20; ++j) acc[j] = (float4v){0.f, 0.f, 0.f, 0.f};

    // ---- prologue
    {
        float4 xa = *(const float4*)xsrc;
        float4 xb = *(const float4*)(xsrc + 4);
        gload16(srcB0, Bs0 + iss0 * 512);
        gload16(srcB1, Bs0 + iss1 * 512);
        if (wid < 4) gload16(srcB2, Bs0 + iss2 * 512);
        half8 h;
        h[0] = (_Float16)xa.x; h[1] = (_Float16)xa.y;
        h[2] = (_Float16)xa.z; h[3] = (_Float16)xa.w;
        h[4] = (_Float16)xb.x; h[5] = (_Float16)xb.y;
        h[6] = (_Float16)xb.z; h[7] = (_Float16)xb.w;
        *(half8*)&As0[tid * 8] = h;
    }
    __syncthreads();

    int cur = 0;
    for (int kk = 0; kk < 16; ++kk) {
        const int k0n = ((kk + 1) & 15) * 32;
        float4 nxa = *(const float4*)(xsrc + k0n);
        float4 nxb = *(const float4*)(xsrc + k0n + 4);
        unsigned short* Bnext = Bs0 + (cur ^ 1) * 10240;
        gload16(srcB0 + k0n, Bnext + iss0 * 512);
        gload16(srcB1 + k0n, Bnext + iss1 * 512);
        if (wid < 4) gload16(srcB2 + k0n, Bnext + iss2 * 512);

        half8 a = *(const half8*)((const char*)(As0 + cur * 4096) + aoff);
        const char* bbase = (const char*)(Bs0 + cur * 10240) + boff;
#pragma unroll
        for (int j = 0; j < 20; ++j) {
            half8 b = *(const half8*)(bbase + j * 1024);
            acc[j] = __builtin_amdgcn_mfma_f32_16x16x32_f16(a, b, acc[j], 0, 0, 0);
        }

        half8 h;
        h[0] = (_Float16)nxa.x; h[1] = (_Float16)nxa.y;
        h[2] = (_Float16)nxa.z; h[3] = (_Float16)nxa.w;
        h[4] = (_Float16)nxb.x; h[5] = (_Float16)nxb.y;
        h[6] = (_Float16)nxb.z; h[7] = (_Float16)nxb.w;
        *(half8*)&As0[(cur ^ 1) * 4096 + tid * 8] = h;

        __syncthreads();
        cur ^= 1;
    }

    // ---- epilogue: 4 slices; slice r holds rows {wid*16+q*4+r} = 32 rows.
    float macc[20];
#pragma unroll
    for (int j = 0; j < 20; ++j) macc[j] = 0.f;
    const int gg = tid >> 4;          // group 0..31 (phase B)
    const int lql = tid & 15;
    const int cb = lql * 20;          // contiguous code base for phase B

    for (int r = 0; r < 4; ++r) {
        // phase A: scatter scores (+bias) into rep[slot][c]
        const int slot = wid * 4 + q;
#pragma unroll
        for (int j = 0; j < 20; ++j)
            rep[slot * REPLD + j * 16 + lq] = acc[j][r] + bqs[j * 16 + lq];
        __syncthreads();

        // phase B: group gg owns row=(gg>>2)*16+(gg&3)*4+r; lane owns 20 contig codes
        const int rowL  = (gg >> 2) * 16 + (gg & 3) * 4 + r;
        const int tglob = tok0 + rowL;
        const float* grow = gum + ((size_t)tglob * GG + g) * CC + cb;
        const float* rrow = rep + gg * REPLD + cb;

        float le[20];
        float s = 0.f;
        float b = -3.0e38f; int bi = 0; float s2 = -3.0e38f;
#pragma unroll
        for (int jj = 0; jj < 5; ++jj) {
            float4 lv = *(const float4*)(rrow + jj * 4);
            float4 gv = *(const float4*)(grow + jj * 4);
            float lf[4] = {lv.x, lv.y, lv.z, lv.w};
            float gf[4] = {gv.x, gv.y, gv.z, gv.w};
#pragma unroll
            for (int t = 0; t < 4; ++t) {
                int j = jj * 4 + t;
                float v = lf[t] + gf[t];
                if (v > b)       { s2 = b; b = v; bi = cb + j; }
                else if (v > s2) { s2 = v; }
                le[j] = __expf(lf[t]); s += le[j];
            }
        }
        // fused 4-step reduce within 16-lane group: sum + (max, idx, second)
#pragma unroll
        for (int m = 1; m < 16; m <<= 1) {
            float os  = __shfl_xor(s,  m, 64);
            float ob  = __shfl_xor(b,  m, 64);
            int   obi = __shfl_xor(bi, m, 64);
            float os2 = __shfl_xor(s2, m, 64);
            s += os;
            if (ob > b || (ob == b && obi < bi)) { s2 = fmaxf(os2, b); b = ob; bi = obi; }
            else                                 { s2 = fmaxf(s2, ob); }
        }
        float inv = 1.f / s;
#pragma unroll
        for (int j = 0; j < 20; ++j) macc[j] += le[j] * inv;

        if (lql == 0 && (b - s2) < MARGIN) {
            int p = atomicAdd(&cnt[g], 1);
            flagsg[p] = tglob;
        }
        const float* cvp = cv + ((size_t)(g * CC + bi)) * DHALF + lql * 8;
        float4 c0v = *(const float4*)cvp;
        float4 c1v = *(const float4*)(cvp + 4);
        float* op = out + (size_t)tglob * 256 + g * DHALF + lql * 8;
        *(float4*)op       = c0v;
        *(float4*)(op + 4) = c1v;
        __syncthreads();
    }

    // macc[j] is lane's sum for code cb+j over its 4 tokens; fold via LDS atomics
#pragma unroll
    for (int j = 0; j < 20; ++j)
        atomicAdd(&smean[cb + j], macc[j]);
    __syncthreads();
    for (int i = tid; i < CC; i += 512)
        atomicAdd(&meanAcc[g * CC + i], smean[i]);
}

// Exact fp32 recompute for flagged rows: FB rows share one W pass.
__global__ __launch_bounds__(320) void fixup(
    const float* __restrict__ X, const float* __restrict__ W,
    const float* __restrict__ bq, const float* __restrict__ gum,
    const float* __restrict__ cv, float* __restrict__ out,
    const int* __restrict__ flags0, const int* __restrict__ flags1,
    const int* __restrict__ cnt)
{
    __shared__ float xs[FB][HID];
    __shared__ float vals[FB][CC];
    __shared__ int stok[FB];
    const int tid = threadIdx.x;
    const int n0 = cnt[0], n1 = cnt[1];
    const int nb0 = (n0 + FB - 1) / FB;
    const int nb1 = (n1 + FB - 1) / FB;

    for (int bb = blockIdx.x; bb < nb0 + nb1; bb += gridDim.x) {
        const int g    = (bb < nb0) ? 0 : 1;
        const int lb   = (bb < nb0) ? bb : bb - nb0;
        const int n    = g ? n1 : n0;
        const int* fl  = g ? flags1 : flags0;
        const int r0   = lb * FB;
        const int nr   = (n - r0 < FB) ? (n - r0) : FB;

        if (tid < FB) {
            int idx = r0 + tid;
            if (idx >= n) idx = n - 1;
            stok[tid] = fl[idx];
        }
        __syncthreads();
        for (int i = tid; i < FB * (HID / 4); i += 320) {
            int r = i >> 7, k4 = i & 127;
            *(float4*)&xs[r][k4 * 4] = *(const float4*)(X + (size_t)stok[r] * HID + k4 * 4);
        }
        __syncthreads();

        {
            const int c = tid;
            if (c < CC) {
                const float* wr = W + (size_t)(g * CC + c) * HID;
                float acc[FB];
#pragma unroll
                for (int r = 0; r < FB; ++r) acc[r] = 0.f;
                for (int k4 = 0; k4 < HID / 4; ++k4) {
                    float4 w4 = *(const float4*)(wr + k4 * 4);
#pragma unroll
                    for (int r = 0; r < FB; ++r) {
                        float4 xv = *(const float4*)&xs[r][k4 * 4];
                        acc[r] = fmaf(xv.x, w4.x, acc[r]);
                        acc[r] = fmaf(xv.y, w4.y, acc[r]);
                        acc[r] = fmaf(xv.z, w4.z, acc[r]);
                        acc[r] = fmaf(xv.w, w4.w, acc[r]);
                    }
                }
                float bias = bq[g * CC + c];
#pragma unroll
                for (int r = 0; r < FB; ++r)
                    vals[r][c] = acc[r] + bias + gum[((size_t)stok[r] * GG + g) * CC + c];
            }
        }
        __syncthreads();

        const int lane = tid & 63;
        const int wv   = tid >> 6;
        if (wv < FB) {
            const int r = wv;
            if (r < nr) {
                float b = -3.0e38f; int bi = 0;
#pragma unroll
                for (int j = 0; j < 5; ++j) {
                    int c = lane + j * 64;
                    float v = vals[r][c];
                    if (v > b || (v == b && c < bi)) { b = v; bi = c; }
                }
#pragma unroll
                for (int m = 32; m; m >>= 1) {
                    float ob = __shfl_xor(b, m, 64);
                    int  obi = __shfl_xor(bi, m, 64);
                    if (ob > b || (ob == b && obi < bi)) { b = ob; bi = obi; }
                }
                int tok = stok[r];
                float2 cvv = *(const float2*)(cv + ((size_t)(g * CC + bi)) * DHALF + lane * 2);
                *(float2*)(out + (size_t)tok * 256 + g * DHALF + lane * 2) = cvv;
            }
        }
        __syncthreads();
    }
}

__global__ __launch_bounds__(256) void perpk(
    const float* __restrict__ meanAcc, float* __restrict__ outp, int ntot)
{
    __shared__ float red0[256];
    __shared__ float red1[256];
    const float invn = 1.f / (float)ntot;
    float h0 = 0.f, h1 = 0.f;
    for (int c = threadIdx.x; c < CC; c += 256) {
        float p0 = meanAcc[c]      * invn;
        float p1 = meanAcc[CC + c] * invn;
        h0 -= p0 * logf(p0 + 1e-7f);
        h1 -= p1 * logf(p1 + 1e-7f);
    }
    red0[threadIdx.x] = h0; red1[threadIdx.x] = h1;
    __syncthreads();
    for (int s = 128; s; s >>= 1) {
        if (threadIdx.x < (unsigned)s) {
            red0[threadIdx.x] += red0[threadIdx.x + s];
            red1[threadIdx.x] += red1[threadIdx.x + s];
        }
        __syncthreads();
    }
    if (threadIdx.x == 0) outp[0] = expf(red0[0]) + expf(red1[0]);
}

extern "C" void kernel_launch(void* const* d_in, const int* in_sizes, int n_in,
                              void* d_out, int out_size, void* d_ws, size_t ws_size,
                              hipStream_t stream) {
    const float* x      = (const float*)d_in[0];
    const float* gumbel = (const float*)d_in[1];
    const float* Wq     = (const float*)d_in[2];
    const float* bq     = (const float*)d_in[3];
    const float* cv     = (const float*)d_in[4];
    float* out = (float*)d_out;

    const int NT = in_sizes[0] / HID;       // 32768 tokens

    char* wsc = (char*)d_ws;
    float* meanAcc = (float*)wsc;                          // 640 f
    int*   cnt     = (int*)(wsc + 2560);                   // 2 ints
    int*   flags0  = (int*)(wsc + 4096);                   // 32768 ints
    int*   flags1  = (int*)(wsc + 135168);                 // 32768 ints
    unsigned short* Wh = (unsigned short*)(wsc + 266240);  // 640*512 f16

    zero_misc<<<1, 256, 0, stream>>>(meanAcc, cnt);
    convert_f16<<<(GC * HID / 8 + 255) / 256, 256, 0, stream>>>(Wq, Wh, GC * HID / 8);

    const int nwg = (NT / 128) * 2;         // 512 blocks = 2 per CU
    fused<<<nwg, 512, 0, stream>>>(x, Wh, bq, gumbel, cv, out,
                                   meanAcc, cnt, flags0, flags1);

    fixup<<<256, 320, 0, stream>>>(x, Wq, bq, gumbel, cv, out, flags0, flags1, cnt);
    perpk<<<1, 256, 0, stream>>>(meanAcc, out + (size_t)out_size - 1, NT);
}

// Round 10
// 125.563 us; speedup vs baseline: 1.4370x; 1.4370x over previous
//
#include <hip/hip_runtime.h>
#include <hip/hip_fp16.h>

#define HID 512
#define GC  640
#define CC  320
#define GG  2
#define DHALF 128
#define MARGIN 0.004f
#define FB 4
#define REPLD 324   // padded row stride (dwords) for the repack buffer

typedef __attribute__((ext_vector_type(8))) _Float16 half8;
typedef __attribute__((ext_vector_type(4))) float float4v;

__device__ __forceinline__ void gload16(const void* g, void* l) {
    __builtin_amdgcn_global_load_lds(
        (const __attribute__((address_space(1))) void*)(unsigned long long)g,
        (__attribute__((address_space(3))) void*)(unsigned)(unsigned long long)l,
        16, 0, 0);
}

__global__ __launch_bounds__(256) void zero_misc(float* meanAcc, int* cnt) {
    for (int i = threadIdx.x; i < GC; i += 256) meanAcc[i] = 0.f;
    if (threadIdx.x < 2) cnt[threadIdx.x] = 0;
}

__global__ __launch_bounds__(256) void convert_f16(
    const float* __restrict__ in, unsigned short* __restrict__ out, int n8)
{
    int i = blockIdx.x * 256 + threadIdx.x;
    if (i >= n8) return;
    const float4* p = (const float4*)in + (size_t)i * 2;
    float4 v0 = p[0], v1 = p[1];
    float f[8] = {v0.x, v0.y, v0.z, v0.w, v1.x, v1.y, v1.z, v1.w};
    unsigned r[4];
#pragma unroll
    for (int j = 0; j < 4; ++j) {
        __half2 hh = __float22half2_rn(make_float2(f[2*j], f[2*j+1]));
        r[j] = __builtin_bit_cast(unsigned, hh);
    }
    uint4 o = {r[0], r[1], r[2], r[3]};
    *(uint4*)(out + (size_t)i * 8) = o;
}

// Fused GEMM + LDS-repack epilogue. Block: 64 tokens x 320 codes (one group).
// 8 waves = 4 row-groups x 2 col-halves; each wave 16 rows x 160 cols ->
// acc[10] = 40 VGPR (fits 128-reg cap at 2 blocks/CU: NO spills).
// K-loop staging/swizzles identical to round 8 (verified, 0 conflicts).
__global__ __launch_bounds__(512, 4) void fused(
    const float* __restrict__ X, const unsigned short* __restrict__ Wh,
    const float* __restrict__ bq, const float* __restrict__ gum,
    const float* __restrict__ cv, float* __restrict__ out,
    float* __restrict__ meanAcc, int* __restrict__ cnt,
    int* __restrict__ flags0, int* __restrict__ flags1)
{
    __shared__ __align__(16) char lds[49152];               // 48 KB
    unsigned short* As0 = (unsigned short*)lds;             // [2][2048] halves (8 KB)
    unsigned short* Bs0 = (unsigned short*)(lds + 8192);    // [2][10240] halves (40 KB)
    float* rep = (float*)lds;                               // epilogue [16][REPLD]
    __shared__ float bqs[CC];
    __shared__ float smean[CC];

    const int tid  = threadIdx.x;
    const int lane = tid & 63;
    const int wid  = tid >> 6;          // 0..7
    const int wr   = wid >> 1;          // row-group 0..3
    const int wc   = wid & 1;           // col-half 0..1
    const int lq   = lane & 15;
    const int q    = lane >> 4;

    int bid = blockIdx.x, nwg = gridDim.x;
    int swz = ((nwg & 7) == 0) ? (bid & 7) * (nwg >> 3) + (bid >> 3) : bid;
    const int g    = swz & 1;
    const int tok0 = (swz >> 1) * 64;
    int* flagsg = g ? flags1 : flags0;

    for (int i = tid; i < CC; i += 512) { bqs[i] = bq[g * CC + i]; smean[i] = 0.f; }

    // ---- B staging (round-8 verbatim): XOR involution on SOURCE chunk, linear dest
    const int iss0 = wid, iss1 = wid + 8, iss2 = wid + 16;  // iss2 only wid<4
    const int c0i = (iss0 * 64 + lane) ^ (((iss0 * 64 + lane) >> 3) & 7);
    const int c1i = (iss1 * 64 + lane) ^ (((iss1 * 64 + lane) >> 3) & 7);
    const int c2i = (iss2 * 64 + lane) ^ (((iss2 * 64 + lane) >> 3) & 7);
    const unsigned short* srcB0 = Wh + ((size_t)(g * CC + (c0i >> 2))) * HID + (c0i & 3) * 8;
    const unsigned short* srcB1 = Wh + ((size_t)(g * CC + (c1i >> 2))) * HID + (c1i & 3) * 8;
    const unsigned short* srcB2 = Wh + ((size_t)(g * CC + (c2i >> 2))) * HID + (c2i & 3) * 8;

    // ---- A staging: 256 chunks (64 rows x 4 slots); threads tid<256 only
    const int ca = tid ^ ((tid >> 3) & 7);
    const float* xsrc = X + (size_t)(tok0 + (ca >> 2)) * HID + (ca & 3) * 8;

    // ---- swizzled read offsets (bytes)
    int aoff = ((wr * 16 + lq) << 6) + (q << 4);            // row = wr*16+lq (0..63)
    aoff ^= ((aoff >> 7) & 7) << 4;
    int boff = (lq << 6) + (q << 4);
    boff ^= ((lq >> 1) & 7) << 4;
    boff += wc * 10240;                                     // col-half: bits>=7, XOR-safe

    float4v acc[10];
#pragma unroll
    for (int j = 0; j < 10; ++j) acc[j] = (float4v){0.f, 0.f, 0.f, 0.f};

    // ---- prologue
    if (tid < 256) {
        float4 xa = *(const float4*)xsrc;
        float4 xb = *(const float4*)(xsrc + 4);
        half8 h;
        h[0] = (_Float16)xa.x; h[1] = (_Float16)xa.y;
        h[2] = (_Float16)xa.z; h[3] = (_Float16)xa.w;
        h[4] = (_Float16)xb.x; h[5] = (_Float16)xb.y;
        h[6] = (_Float16)xb.z; h[7] = (_Float16)xb.w;
        *(half8*)&As0[tid * 8] = h;
    }
    gload16(srcB0, Bs0 + iss0 * 512);
    gload16(srcB1, Bs0 + iss1 * 512);
    if (wid < 4) gload16(srcB2, Bs0 + iss2 * 512);
    __syncthreads();

    int cur = 0;
    for (int kk = 0; kk < 16; ++kk) {
        const int k0n = ((kk + 1) & 15) * 32;
        float4 nxa = {}, nxb = {};
        if (tid < 256) {
            nxa = *(const float4*)(xsrc + k0n);
            nxb = *(const float4*)(xsrc + k0n + 4);
        }
        unsigned short* Bnext = Bs0 + (cur ^ 1) * 10240;
        gload16(srcB0 + k0n, Bnext + iss0 * 512);
        gload16(srcB1 + k0n, Bnext + iss1 * 512);
        if (wid < 4) gload16(srcB2 + k0n, Bnext + iss2 * 512);

        half8 a = *(const half8*)((const char*)(As0 + cur * 2048) + aoff);
        const char* bbase = (const char*)(Bs0 + cur * 10240) + boff;
#pragma unroll
        for (int j = 0; j < 10; ++j) {
            half8 b = *(const half8*)(bbase + j * 1024);
            acc[j] = __builtin_amdgcn_mfma_f32_16x16x32_f16(a, b, acc[j], 0, 0, 0);
        }

        if (tid < 256) {
            half8 h;
            h[0] = (_Float16)nxa.x; h[1] = (_Float16)nxa.y;
            h[2] = (_Float16)nxa.z; h[3] = (_Float16)nxa.w;
            h[4] = (_Float16)nxb.x; h[5] = (_Float16)nxb.y;
            h[6] = (_Float16)nxb.z; h[7] = (_Float16)nxb.w;
            *(half8*)&As0[(cur ^ 1) * 2048 + tid * 8] = h;
        }
        __syncthreads();
        cur ^= 1;
    }

    // ---- epilogue: 4 slices of 16 rows; scores -> rep -> contiguous-code groups
    float macc[20];
#pragma unroll
    for (int j = 0; j < 20; ++j) macc[j] = 0.f;
    const int gg  = tid >> 4;         // 0..31; only gg<16 active in phase B
    const int lql = tid & 15;
    const int cb  = lql * 20;

    for (int r = 0; r < 4; ++r) {
        // phase A: wave (wr,wc) q-group owns slot = wr*4+q (row wr*16+q*4+r),
        // writes its col-half (contiguous 64B runs per j: conflict-free)
        const int slot = wr * 4 + q;
#pragma unroll
        for (int j = 0; j < 10; ++j) {
            const int c = wc * 160 + j * 16 + lq;
            rep[slot * REPLD + c] = acc[j][r] + bqs[c];
        }
        __syncthreads();

        if (gg < 16) {
            const int rowL  = (gg >> 2) * 16 + (gg & 3) * 4 + r;
            const int tglob = tok0 + rowL;
            const float* grow = gum + ((size_t)tglob * GG + g) * CC + cb;
            const float* rrow = rep + gg * REPLD + cb;

            float s = 0.f;
            float b = -3.0e38f; int bi = 0; float s2 = -3.0e38f;
#pragma unroll
            for (int jj = 0; jj < 5; ++jj) {
                float4 lv = *(const float4*)(rrow + jj * 4);
                float4 gv = *(const float4*)(grow + jj * 4);
                float lf[4] = {lv.x, lv.y, lv.z, lv.w};
                float gf[4] = {gv.x, gv.y, gv.z, gv.w};
#pragma unroll
                for (int t = 0; t < 4; ++t) {
                    float v = lf[t] + gf[t];
                    if (v > b)       { s2 = b; b = v; bi = cb + jj * 4 + t; }
                    else if (v > s2) { s2 = v; }
                    s += __expf(lf[t]);
                }
            }
            // fused 4-step reduce in the 16-lane group: sum + (max, idx, second)
#pragma unroll
            for (int m = 1; m < 16; m <<= 1) {
                float os  = __shfl_xor(s,  m, 64);
                float ob  = __shfl_xor(b,  m, 64);
                int   obi = __shfl_xor(bi, m, 64);
                float os2 = __shfl_xor(s2, m, 64);
                s += os;
                if (ob > b || (ob == b && obi < bi)) { s2 = fmaxf(os2, b); b = ob; bi = obi; }
                else                                 { s2 = fmaxf(s2, ob); }
            }
            float inv = 1.f / s;
            // second pass: recompute exp from LDS (saves 20 live VGPRs vs le[])
#pragma unroll
            for (int jj = 0; jj < 5; ++jj) {
                float4 lv = *(const float4*)(rrow + jj * 4);
                macc[jj*4+0] += __expf(lv.x) * inv;
                macc[jj*4+1] += __expf(lv.y) * inv;
                macc[jj*4+2] += __expf(lv.z) * inv;
                macc[jj*4+3] += __expf(lv.w) * inv;
            }

            if (lql == 0 && (b - s2) < MARGIN) {
                int p = atomicAdd(&cnt[g], 1);
                flagsg[p] = tglob;
            }
            const float* cvp = cv + ((size_t)(g * CC + bi)) * DHALF + lql * 8;
            float4 c0v = *(const float4*)cvp;
            float4 c1v = *(const float4*)(cvp + 4);
            float* op = out + (size_t)tglob * 256 + g * DHALF + lql * 8;
            *(float4*)op       = c0v;
            *(float4*)(op + 4) = c1v;
        }
        __syncthreads();
    }

    if (tid < 256) {
#pragma unroll
        for (int j = 0; j < 20; ++j)
            atomicAdd(&smean[cb + j], macc[j]);
    }
    __syncthreads();
    for (int i = tid; i < CC; i += 512)
        atomicAdd(&meanAcc[g * CC + i], smean[i]);
}

// Exact fp32 recompute for flagged rows: FB rows share one W pass.
__global__ __launch_bounds__(320) void fixup(
    const float* __restrict__ X, const float* __restrict__ W,
    const float* __restrict__ bq, const float* __restrict__ gum,
    const float* __restrict__ cv, float* __restrict__ out,
    const int* __restrict__ flags0, const int* __restrict__ flags1,
    const int* __restrict__ cnt)
{
    __shared__ float xs[FB][HID];
    __shared__ float vals[FB][CC];
    __shared__ int stok[FB];
    const int tid = threadIdx.x;
    const int n0 = cnt[0], n1 = cnt[1];
    const int nb0 = (n0 + FB - 1) / FB;
    const int nb1 = (n1 + FB - 1) / FB;

    for (int bb = blockIdx.x; bb < nb0 + nb1; bb += gridDim.x) {
        const int g    = (bb < nb0) ? 0 : 1;
        const int lb   = (bb < nb0) ? bb : bb - nb0;
        const int n    = g ? n1 : n0;
        const int* fl  = g ? flags1 : flags0;
        const int r0   = lb * FB;
        const int nr   = (n - r0 < FB) ? (n - r0) : FB;

        if (tid < FB) {
            int idx = r0 + tid;
            if (idx >= n) idx = n - 1;
            stok[tid] = fl[idx];
        }
        __syncthreads();
        for (int i = tid; i < FB * (HID / 4); i += 320) {
            int r = i >> 7, k4 = i & 127;
            *(float4*)&xs[r][k4 * 4] = *(const float4*)(X + (size_t)stok[r] * HID + k4 * 4);
        }
        __syncthreads();

        {
            const int c = tid;
            if (c < CC) {
                const float* wr = W + (size_t)(g * CC + c) * HID;
                float acc[FB];
#pragma unroll
                for (int r = 0; r < FB; ++r) acc[r] = 0.f;
                for (int k4 = 0; k4 < HID / 4; ++k4) {
                    float4 w4 = *(const float4*)(wr + k4 * 4);
#pragma unroll
                    for (int r = 0; r < FB; ++r) {
                        float4 xv = *(const float4*)&xs[r][k4 * 4];
                        acc[r] = fmaf(xv.x, w4.x, acc[r]);
                        acc[r] = fmaf(xv.y, w4.y, acc[r]);
                        acc[r] = fmaf(xv.z, w4.z, acc[r]);
                        acc[r] = fmaf(xv.w, w4.w, acc[r]);
                    }
                }
                float bias = bq[g * CC + c];
#pragma unroll
                for (int r = 0; r < FB; ++r)
                    vals[r][c] = acc[r] + bias + gum[((size_t)stok[r] * GG + g) * CC + c];
            }
        }
        __syncthreads();

        const int lane = tid & 63;
        const int wv   = tid >> 6;
        if (wv < FB) {
            const int r = wv;
            if (r < nr) {
                float b = -3.0e38f; int bi = 0;
#pragma unroll
                for (int j = 0; j < 5; ++j) {
                    int c = lane + j * 64;
                    float v = vals[r][c];
                    if (v > b || (v == b && c < bi)) { b = v; bi = c; }
                }
#pragma unroll
                for (int m = 32; m; m >>= 1) {
                    float ob = __shfl_xor(b, m, 64);
                    int  obi = __shfl_xor(bi, m, 64);
                    if (ob > b || (ob == b && obi < bi)) { b = ob; bi = obi; }
                }
                int tok = stok[r];
                float2 cvv = *(const float2*)(cv + ((size_t)(g * CC + bi)) * DHALF + lane * 2);
                *(float2*)(out + (size_t)tok * 256 + g * DHALF + lane * 2) = cvv;
            }
        }
        __syncthreads();
    }
}

__global__ __launch_bounds__(256) void perpk(
    const float* __restrict__ meanAcc, float* __restrict__ outp, int ntot)
{
    __shared__ float red0[256];
    __shared__ float red1[256];
    const float invn = 1.f / (float)ntot;
    float h0 = 0.f, h1 = 0.f;
    for (int c = threadIdx.x; c < CC; c += 256) {
        float p0 = meanAcc[c]      * invn;
        float p1 = meanAcc[CC + c] * invn;
        h0 -= p0 * logf(p0 + 1e-7f);
        h1 -= p1 * logf(p1 + 1e-7f);
    }
    red0[threadIdx.x] = h0; red1[threadIdx.x] = h1;
    __syncthreads();
    for (int s = 128; s; s >>= 1) {
        if (threadIdx.x < (unsigned)s) {
            red0[threadIdx.x] += red0[threadIdx.x + s];
            red1[threadIdx.x] += red1[threadIdx.x + s];
        }
        __syncthreads();
    }
    if (threadIdx.x == 0) outp[0] = expf(red0[0]) + expf(red1[0]);
}

extern "C" void kernel_launch(void* const* d_in, const int* in_sizes, int n_in,
                              void* d_out, int out_size, void* d_ws, size_t ws_size,
                              hipStream_t stream) {
    const float* x      = (const float*)d_in[0];
    const float* gumbel = (const float*)d_in[1];
    const float* Wq     = (const float*)d_in[2];
    const float* bq     = (const float*)d_in[3];
    const float* cv     = (const float*)d_in[4];
    float* out = (float*)d_out;

    const int NT = in_sizes[0] / HID;       // 32768 tokens

    char* wsc = (char*)d_ws;
    float* meanAcc = (float*)wsc;                          // 640 f
    int*   cnt     = (int*)(wsc + 2560);                   // 2 ints
    int*   flags0  = (int*)(wsc + 4096);                   // 32768 ints
    int*   flags1  = (int*)(wsc + 135168);                 // 32768 ints
    unsigned short* Wh = (unsigned short*)(wsc + 266240);  // 640*512 f16

    zero_misc<<<1, 256, 0, stream>>>(meanAcc, cnt);
    convert_f16<<<(GC * HID / 8 + 255) / 256, 256, 0, stream>>>(Wq, Wh, GC * HID / 8);

    const int nwg = (NT / 64) * 2;          // 1024 blocks
    fused<<<nwg, 512, 0, stream>>>(x, Wh, bq, gumbel, cv, out,
                                   meanAcc, cnt, flags0, flags1);

    fixup<<<256, 320, 0, stream>>>(x, Wq, bq, gumbel, cv, out, flags0, flags1, cnt);
    perpk<<<1, 256, 0, stream>>>(meanAcc, out + (size_t)out_size - 1, NT);
}